// Round 12
// baseline (622.364 us; speedup 1.0000x reference)
//
#include <hip/hip_runtime.h>

#define N_NODES 50000
#define DIM 128
#define N_LAYERS 5
#define BN_EPS 1e-5f

typedef __attribute__((ext_vector_type(8))) short short8;
typedef __attribute__((ext_vector_type(4))) float f32x4;

__device__ __forceinline__ float bf2f(unsigned int u16) {
    union { unsigned int i; float f; } c; c.i = u16 << 16; return c.f;
}
__device__ __forceinline__ unsigned short f2bf(float f) {
    union { float f; unsigned int i; } c; c.f = f;
    unsigned int v = c.i + 0x7FFFu + ((c.i >> 16) & 1u);   // RNE
    return (unsigned short)(v >> 16);
}

// ---------------- CSR build ----------------

__global__ void hist_kernel(const int* __restrict__ dst, int n_edges, int* __restrict__ counts) {
    int e = blockIdx.x * 256 + threadIdx.x;
    if (e < n_edges) atomicAdd(&counts[dst[e]], 1);
}

__global__ void scan_local(const int* __restrict__ counts, int n,
                           int* __restrict__ offsets, int* __restrict__ blocksums) {
    __shared__ int temp[256];
    int t = threadIdx.x;
    int i = blockIdx.x * 256 + t;
    int v = (i < n) ? counts[i] : 0;
    temp[t] = v;
    __syncthreads();
    for (int off = 1; off < 256; off <<= 1) {
        int add = (t >= off) ? temp[t - off] : 0;
        __syncthreads();
        temp[t] += add;
        __syncthreads();
    }
    if (i < n) offsets[i] = temp[t] - v;
    if (t == 255) blocksums[blockIdx.x] = temp[255];
}

__global__ void scan_block(int* __restrict__ blocksums, int nb) {
    __shared__ int temp[256];
    int t = threadIdx.x;
    int v = (t < nb) ? blocksums[t] : 0;
    temp[t] = v;
    __syncthreads();
    for (int off = 1; off < 256; off <<= 1) {
        int add = (t >= off) ? temp[t - off] : 0;
        __syncthreads();
        temp[t] += add;
        __syncthreads();
    }
    if (t < nb) blocksums[t] = temp[t] - v;
}

__global__ void scan_add(int* __restrict__ offsets, int* __restrict__ cursor,
                         const int* __restrict__ blocksums, int n, int n_edges) {
    int i = blockIdx.x * 256 + threadIdx.x;
    if (i < n) {
        int val = offsets[i] + blocksums[blockIdx.x];
        offsets[i] = val;
        cursor[i] = val;
    }
    if (i == 0) offsets[n] = n_edges;
}

__global__ void scatter_kernel(const int* __restrict__ src, const int* __restrict__ dst,
                               int n_edges, int* __restrict__ cursor, int* __restrict__ csr_src) {
    int e = blockIdx.x * 256 + threadIdx.x;
    if (e < n_edges) {
        int p = atomicAdd(&cursor[dst[e]], 1);
        csr_src[p] = src[e];
    }
}

// ---------------- prep ----------------

// pack W1/W2 (all layers) into MFMA B-fragment order, hi+lo bf16 planes.
__global__ void wpack_prep(const float* __restrict__ W1, const float* __restrict__ W2,
                           unsigned short* __restrict__ wp) {
    int idx = blockIdx.x * 256 + threadIdx.x;
    if (idx >= N_LAYERS * 2 * 16384) return;
    int j    = idx & 7;
    int lane = (idx >> 3) & 63;
    int nt   = (idx >> 9) & 7;
    int ks   = (idx >> 12) & 3;
    int mat  = (idx >> 14) & 1;
    int lay  = idx >> 15;
    int l15 = lane & 15, l4 = lane >> 4;
    int col = nt * 16 + l15;
    int kp = ks * 32 + l4 * 8 + j;
    int k = mat ? ((kp & 7) * 16 + (kp >> 3)) : kp;
    const float* W = mat ? W2 : W1;
    float w = W[((size_t)lay * 128 + k) * 128 + col];
    unsigned short hi = f2bf(w);
    unsigned short lo = f2bf(w - bf2f(hi));
    size_t base = (size_t)(lay * 2 + mat) * 32768;
    size_t inner = (size_t)((ks * 8 + nt) * 64 + lane) * 8 + j;
    wp[base + inner] = hi;
    wp[base + 16384 + inner] = lo;
}

// ---------------- per-layer aggregation (column-pass split) ----------------
// Pass p touches only bytes [128p, 128p+128) of each feature row, so the
// per-pass gather working set is 50k x 128B = 6.4 MB (near-L2-resident per
// XCD) instead of 12.8/25.6 MB. Temporal separation across passes comes from
// separate kernel launches.

// layer-0 (fp32 rows, 512B): 4 passes. 8 lanes x float4 per 128B chunk,
// 8 edges per instruction, depth-8 = 64 edges in flight per wave.
__global__ void agg_pass_fp32(const float4* __restrict__ x4, const int* __restrict__ csr_src,
                              const int* __restrict__ offsets, int pass,
                              unsigned int* __restrict__ h_hi_u, unsigned int* __restrict__ h_lo_u) {
    int wave = threadIdx.x >> 6;
    int l = threadIdx.x & 63;
    int node = blockIdx.x * 4 + wave;
    if (node >= N_NODES) return;
    int g = l >> 3;              // edge slot 0..7
    int d = l & 7;               // float4 chunk within the pass's 128B
    int cbase = pass * 8 + d;    // float4 index within the 32-float4 row
    int beg = offsets[node], end = offsets[node + 1];

    float4 acc = make_float4(0.f, 0.f, 0.f, 0.f);
    if (g == 0) acc = x4[(size_t)node * 32 + cbase];   // self term once

    for (int e = beg; e < end; e += 64) {
        int s[8];
#pragma unroll
        for (int i = 0; i < 8; ++i) s[i] = csr_src[min(e + 8 * i + g, end - 1)];
        float4 v[8];
#pragma unroll
        for (int i = 0; i < 8; ++i) v[i] = x4[(size_t)s[i] * 32 + cbase];
#pragma unroll
        for (int i = 0; i < 8; ++i) {
            float w = (e + 8 * i + g < end) ? 1.0f : 0.0f;   // mask tail
            acc.x = fmaf(v[i].x, w, acc.x);
            acc.y = fmaf(v[i].y, w, acc.y);
            acc.z = fmaf(v[i].z, w, acc.z);
            acc.w = fmaf(v[i].w, w, acc.w);
        }
    }

    // reduce across the 8 edge slots (lanes sharing d)
    acc.x += __shfl_xor(acc.x, 8);  acc.y += __shfl_xor(acc.y, 8);
    acc.z += __shfl_xor(acc.z, 8);  acc.w += __shfl_xor(acc.w, 8);
    acc.x += __shfl_xor(acc.x, 16); acc.y += __shfl_xor(acc.y, 16);
    acc.z += __shfl_xor(acc.z, 16); acc.w += __shfl_xor(acc.w, 16);
    acc.x += __shfl_xor(acc.x, 32); acc.y += __shfl_xor(acc.y, 32);
    acc.z += __shfl_xor(acc.z, 32); acc.w += __shfl_xor(acc.w, 32);

    unsigned short h0 = f2bf(acc.x), h1 = f2bf(acc.y);
    unsigned short h2 = f2bf(acc.z), h3 = f2bf(acc.w);
    if (g == 0) {
        uint2 hv;
        hv.x = (unsigned int)h0 | ((unsigned int)h1 << 16);
        hv.y = (unsigned int)h2 | ((unsigned int)h3 << 16);
        ((uint2*)h_hi_u)[(size_t)node * 32 + cbase] = hv;
    } else if (g == 1) {
        unsigned short l0 = f2bf(acc.x - bf2f(h0)), l1 = f2bf(acc.y - bf2f(h1));
        unsigned short l2 = f2bf(acc.z - bf2f(h2)), l3 = f2bf(acc.w - bf2f(h3));
        uint2 lv;
        lv.x = (unsigned int)l0 | ((unsigned int)l1 << 16);
        lv.y = (unsigned int)l2 | ((unsigned int)l3 << 16);
        ((uint2*)h_lo_u)[(size_t)node * 32 + cbase] = lv;
    }
}

// layers 1..4 (bf16 rows, 256B): 2 passes. 16 lanes x uint2 per 128B chunk,
// 4 edges per instruction, depth-8 = 32 edges in flight per wave.
__global__ void agg_pass_bf(const uint2* __restrict__ xb2, const int* __restrict__ csr_src,
                            const int* __restrict__ offsets, int pass,
                            unsigned int* __restrict__ h_hi_u, unsigned int* __restrict__ h_lo_u) {
    int wave = threadIdx.x >> 6;
    int l = threadIdx.x & 63;
    int node = blockIdx.x * 4 + wave;
    if (node >= N_NODES) return;
    int g = l >> 4;              // edge slot 0..3
    int d = l & 15;              // uint2 chunk within the pass's 128B
    int cbase = pass * 16 + d;   // uint2 index within the 32-uint2 row
    int beg = offsets[node], end = offsets[node + 1];

    float a0 = 0.f, a1 = 0.f, a2 = 0.f, a3 = 0.f;
    if (g == 0) {
        uint2 u = xb2[(size_t)node * 32 + cbase];   // self term once
        a0 = bf2f(u.x & 0xFFFFu); a1 = bf2f(u.x >> 16);
        a2 = bf2f(u.y & 0xFFFFu); a3 = bf2f(u.y >> 16);
    }

    for (int e = beg; e < end; e += 32) {
        int s[8];
#pragma unroll
        for (int i = 0; i < 8; ++i) s[i] = csr_src[min(e + 4 * i + g, end - 1)];
        uint2 v[8];
#pragma unroll
        for (int i = 0; i < 8; ++i) v[i] = xb2[(size_t)s[i] * 32 + cbase];
#pragma unroll
        for (int i = 0; i < 8; ++i) {
            float w = (e + 4 * i + g < end) ? 1.0f : 0.0f;   // mask tail
            a0 = fmaf(bf2f(v[i].x & 0xFFFFu), w, a0);
            a1 = fmaf(bf2f(v[i].x >> 16),     w, a1);
            a2 = fmaf(bf2f(v[i].y & 0xFFFFu), w, a2);
            a3 = fmaf(bf2f(v[i].y >> 16),     w, a3);
        }
    }

    // reduce across the 4 edge slots
    a0 += __shfl_xor(a0, 16); a1 += __shfl_xor(a1, 16);
    a2 += __shfl_xor(a2, 16); a3 += __shfl_xor(a3, 16);
    a0 += __shfl_xor(a0, 32); a1 += __shfl_xor(a1, 32);
    a2 += __shfl_xor(a2, 32); a3 += __shfl_xor(a3, 32);

    unsigned short h0 = f2bf(a0), h1 = f2bf(a1), h2 = f2bf(a2), h3 = f2bf(a3);
    if (g == 0) {
        uint2 hv;
        hv.x = (unsigned int)h0 | ((unsigned int)h1 << 16);
        hv.y = (unsigned int)h2 | ((unsigned int)h3 << 16);
        ((uint2*)h_hi_u)[(size_t)node * 32 + cbase] = hv;
    } else if (g == 1) {
        unsigned short l0 = f2bf(a0 - bf2f(h0)), l1 = f2bf(a1 - bf2f(h1));
        unsigned short l2 = f2bf(a2 - bf2f(h2)), l3 = f2bf(a3 - bf2f(h3));
        uint2 lv;
        lv.x = (unsigned int)l0 | ((unsigned int)l1 << 16);
        lv.y = (unsigned int)l2 | ((unsigned int)l3 << 16);
        ((uint2*)h_lo_u)[(size_t)node * 32 + cbase] = lv;
    }
}

// fused MFMA MLP (bf16x2 split, 3-product): ReLU(h@W1+b1)@W2+b2 -> ReLU
// -> h_raw (fp32) + per-block BN partials
__global__ __launch_bounds__(128) void mlp_mfma(
        const unsigned short* __restrict__ h_hi, const unsigned short* __restrict__ h_lo,
        const short8* __restrict__ wp1, const float* __restrict__ b1,
        const short8* __restrict__ wp2, const float* __restrict__ b2,
        float* __restrict__ h_raw,
        float* __restrict__ part_s, float* __restrict__ part_q) {
    __shared__ unsigned short mid_hi[2][2][16][128];   // [wave][m][row][kp], XOR-swizzled
    __shared__ unsigned short mid_lo[2][2][16][128];
    __shared__ float red_s[2][128], red_q[2][128];
    int t = threadIdx.x, wave = t >> 6, l = t & 63;
    int l15 = l & 15, l4 = l >> 4;
    int row_base = blockIdx.x * 64 + wave * 32;

    int r0 = row_base + l15, r1 = r0 + 16;
    int cr0 = min(r0, N_NODES - 1), cr1 = min(r1, N_NODES - 1);
    const short8* ah0p = (const short8*)(h_hi + (size_t)cr0 * 128);
    const short8* ah1p = (const short8*)(h_hi + (size_t)cr1 * 128);
    const short8* al0p = (const short8*)(h_lo + (size_t)cr0 * 128);
    const short8* al1p = (const short8*)(h_lo + (size_t)cr1 * 128);

    const short8* wp1l = wp1 + 2048;   // lo plane
    const short8* wp2l = wp2 + 2048;

    f32x4 acc[2][8];
#pragma unroll
    for (int m = 0; m < 2; ++m)
#pragma unroll
        for (int nt = 0; nt < 8; ++nt) acc[m][nt] = (f32x4)0.0f;

#pragma unroll
    for (int ks = 0; ks < 4; ++ks) {
        short8 ah0 = ah0p[ks * 4 + l4];
        short8 ah1 = ah1p[ks * 4 + l4];
        short8 al0 = al0p[ks * 4 + l4];
        short8 al1 = al1p[ks * 4 + l4];
#pragma unroll
        for (int nt = 0; nt < 8; ++nt) {
            short8 whi = wp1[(ks * 8 + nt) * 64 + l];
            short8 wlo = wp1l[(ks * 8 + nt) * 64 + l];
            acc[0][nt] = __builtin_amdgcn_mfma_f32_16x16x32_bf16(ah0, whi, acc[0][nt], 0, 0, 0);
            acc[0][nt] = __builtin_amdgcn_mfma_f32_16x16x32_bf16(al0, whi, acc[0][nt], 0, 0, 0);
            acc[0][nt] = __builtin_amdgcn_mfma_f32_16x16x32_bf16(ah0, wlo, acc[0][nt], 0, 0, 0);
            acc[1][nt] = __builtin_amdgcn_mfma_f32_16x16x32_bf16(ah1, whi, acc[1][nt], 0, 0, 0);
            acc[1][nt] = __builtin_amdgcn_mfma_f32_16x16x32_bf16(al1, whi, acc[1][nt], 0, 0, 0);
            acc[1][nt] = __builtin_amdgcn_mfma_f32_16x16x32_bf16(ah1, wlo, acc[1][nt], 0, 0, 0);
        }
    }

    float b1v[8];
#pragma unroll
    for (int nt = 0; nt < 8; ++nt) b1v[nt] = b1[nt * 16 + l15];

#pragma unroll
    for (int m = 0; m < 2; ++m) {
#pragma unroll
        for (int rr = 0; rr < 4; ++rr) {
            int row = l4 * 4 + rr;
            short8 ph, pl;
#pragma unroll
            for (int nt = 0; nt < 8; ++nt) {
                float v = fmaxf(acc[m][nt][rr] + b1v[nt], 0.0f);
                unsigned short hv = f2bf(v);
                ph[nt] = (short)hv;
                pl[nt] = (short)f2bf(v - bf2f(hv));
            }
            int off = (l15 * 16) ^ ((row & 7) << 4);
            *(short8*)((char*)&mid_hi[wave][m][row][0] + off) = ph;
            *(short8*)((char*)&mid_lo[wave][m][row][0] + off) = pl;
        }
    }
    __syncthreads();

    f32x4 acc2[2][8];
#pragma unroll
    for (int m = 0; m < 2; ++m)
#pragma unroll
        for (int nt = 0; nt < 8; ++nt) acc2[m][nt] = (f32x4)0.0f;

#pragma unroll
    for (int ks = 0; ks < 4; ++ks) {
        int off = (ks * 64 + l4 * 16) ^ ((l15 & 7) << 4);
        short8 ah0 = *(const short8*)((char*)&mid_hi[wave][0][l15][0] + off);
        short8 ah1 = *(const short8*)((char*)&mid_hi[wave][1][l15][0] + off);
        short8 al0 = *(const short8*)((char*)&mid_lo[wave][0][l15][0] + off);
        short8 al1 = *(const short8*)((char*)&mid_lo[wave][1][l15][0] + off);
#pragma unroll
        for (int nt = 0; nt < 8; ++nt) {
            short8 whi = wp2[(ks * 8 + nt) * 64 + l];
            short8 wlo = wp2l[(ks * 8 + nt) * 64 + l];
            acc2[0][nt] = __builtin_amdgcn_mfma_f32_16x16x32_bf16(ah0, whi, acc2[0][nt], 0, 0, 0);
            acc2[0][nt] = __builtin_amdgcn_mfma_f32_16x16x32_bf16(al0, whi, acc2[0][nt], 0, 0, 0);
            acc2[0][nt] = __builtin_amdgcn_mfma_f32_16x16x32_bf16(ah0, wlo, acc2[0][nt], 0, 0, 0);
            acc2[1][nt] = __builtin_amdgcn_mfma_f32_16x16x32_bf16(ah1, whi, acc2[1][nt], 0, 0, 0);
            acc2[1][nt] = __builtin_amdgcn_mfma_f32_16x16x32_bf16(al1, whi, acc2[1][nt], 0, 0, 0);
            acc2[1][nt] = __builtin_amdgcn_mfma_f32_16x16x32_bf16(ah1, wlo, acc2[1][nt], 0, 0, 0);
        }
    }

    float b2v[8];
#pragma unroll
    for (int nt = 0; nt < 8; ++nt) b2v[nt] = b2[nt * 16 + l15];

    float s[8], q[8];
#pragma unroll
    for (int nt = 0; nt < 8; ++nt) { s[nt] = 0.0f; q[nt] = 0.0f; }

#pragma unroll
    for (int m = 0; m < 2; ++m) {
#pragma unroll
        for (int rr = 0; rr < 4; ++rr) {
            int rg = row_base + m * 16 + l4 * 4 + rr;
            bool ok = rg < N_NODES;
#pragma unroll
            for (int nt = 0; nt < 8; ++nt) {
                float v = fmaxf(acc2[m][nt][rr] + b2v[nt], 0.0f);   // outer ReLU
                if (ok) {
                    h_raw[(size_t)rg * 128 + nt * 16 + l15] = v;
                    s[nt] += v;
                    q[nt] += v * v;
                }
            }
        }
    }
#pragma unroll
    for (int nt = 0; nt < 8; ++nt) {
        s[nt] += __shfl_xor(s[nt], 16); s[nt] += __shfl_xor(s[nt], 32);
        q[nt] += __shfl_xor(q[nt], 16); q[nt] += __shfl_xor(q[nt], 32);
    }
    if (l4 == 0) {
#pragma unroll
        for (int nt = 0; nt < 8; ++nt) {
            red_s[wave][nt * 16 + l15] = s[nt];
            red_q[wave][nt * 16 + l15] = q[nt];
        }
    }
    __syncthreads();
    if (t < 128) {
        part_s[blockIdx.x * 128 + t] = red_s[0][t] + red_s[1][t];
        part_q[blockIdx.x * 128 + t] = red_q[0][t] + red_q[1][t];
    }
}

// 256 blocks: block b reduces channel (b&127) of (b>>7 ? part_q : part_s)
__global__ __launch_bounds__(256) void bn_reduce(
        const float* __restrict__ part_s, const float* __restrict__ part_q,
        float* __restrict__ bn_sum, float* __restrict__ bn_sq, int nparts) {
    __shared__ float red[256];
    int c = blockIdx.x & 127;
    const float* src = (blockIdx.x >> 7) ? part_q : part_s;
    float* dst = (blockIdx.x >> 7) ? bn_sq : bn_sum;
    float a = 0.0f;
    for (int p = threadIdx.x; p < nparts; p += 256) a += src[p * 128 + c];
    red[threadIdx.x] = a;
    __syncthreads();
    for (int s = 128; s > 0; s >>= 1) {
        if (threadIdx.x < s) red[threadIdx.x] += red[threadIdx.x + s];
        __syncthreads();
    }
    if (threadIdx.x == 0) dst[c] = red[0];
}

// normalize in place (fp32); optionally emit bf16 next-layer input and/or fp32 dup
__global__ void bn_apply(float* __restrict__ h,
                         const float* __restrict__ bn_sum, const float* __restrict__ bn_sq,
                         const float* __restrict__ gamma, const float* __restrict__ beta,
                         uint2* __restrict__ xbf_next, float4* __restrict__ dup) {
    int i4 = blockIdx.x * 256 + threadIdx.x;
    if (i4 >= N_NODES * DIM / 4) return;
    float4 v = ((const float4*)h)[i4];
    int c0 = (i4 & 31) * 4;
    const float invN = 1.0f / (float)N_NODES;
    float* vp = (float*)&v;
#pragma unroll
    for (int j = 0; j < 4; ++j) {
        int c = c0 + j;
        float mean = bn_sum[c] * invN;
        float var = fmaxf(bn_sq[c] * invN - mean * mean, 0.0f);
        float inv = rsqrtf(var + BN_EPS);
        vp[j] = (vp[j] - mean) * inv * gamma[c] + beta[c];
    }
    ((float4*)h)[i4] = v;
    if (xbf_next) {
        unsigned int lo = (unsigned int)f2bf(vp[0]) | ((unsigned int)f2bf(vp[1]) << 16);
        unsigned int hi = (unsigned int)f2bf(vp[2]) | ((unsigned int)f2bf(vp[3]) << 16);
        xbf_next[i4] = make_uint2(lo, hi);
    }
    if (dup) dup[i4] = v;
}

// ---------------- launch ----------------

extern "C" void kernel_launch(void* const* d_in, const int* in_sizes, int n_in,
                              void* d_out, int out_size, void* d_ws, size_t ws_size,
                              hipStream_t stream) {
    const float* x     = (const float*)d_in[0];
    const int*   eidx  = (const int*)d_in[1];
    const float* W1    = (const float*)d_in[3];
    const float* b1    = (const float*)d_in[4];
    const float* W2    = (const float*)d_in[5];
    const float* b2    = (const float*)d_in[6];
    const float* gamma = (const float*)d_in[7];
    const float* beta  = (const float*)d_in[8];

    int n_edges = in_sizes[1] / 2;
    const int* src = eidx;
    const int* dst = eidx + n_edges;

    const int NBLK = (N_NODES + 63) / 64;    // 782 mlp blocks

    int* counts    = (int*)d_ws;                       // 50000
    int* offsets   = counts + N_NODES;                 // 50001
    int* cursor    = offsets + N_NODES + 1;            // 50000
    int* blocksums = cursor + N_NODES;                 // 256
    int* csr_src   = blocksums + 256;                  // n_edges
    float* part_s  = (float*)(csr_src + n_edges);      // NBLK*128
    float* part_q  = part_s + NBLK * 128;              // NBLK*128
    float* bn_sum  = part_q + NBLK * 128;              // 128
    float* bn_sq   = bn_sum + DIM;                     // 128
    size_t wp_off = (((size_t)(bn_sq + DIM) - (size_t)d_ws) + 15) & ~(size_t)15;
    unsigned short* wp = (unsigned short*)((char*)d_ws + wp_off);   // 5*2*32768 bf16 (hi+lo)
    // bf16 next-layer input (written by bn_apply for layers 0..3), 16B aligned
    size_t xb_off = (wp_off + (size_t)N_LAYERS * 2 * 32768 * 2 + 15) & ~(size_t)15;
    uint2* x_bf2 = (uint2*)((char*)d_ws + xb_off);                  // [N][32] uint2 = 12.8 MB

    float* out = (float*)d_out;
    // slot 0 doubles as bf16 hi/lo scratch until the last layer writes it
    unsigned int* h_hi_u = (unsigned int*)d_out;                    // [N][64] uints
    unsigned int* h_lo_u = h_hi_u + (size_t)N_NODES * 64;
    const unsigned short* h_hi = (const unsigned short*)h_hi_u;
    const unsigned short* h_lo = (const unsigned short*)h_lo_u;

    // CSR build
    hipMemsetAsync(counts, 0, N_NODES * sizeof(int), stream);
    hist_kernel<<<(n_edges + 255) / 256, 256, 0, stream>>>(dst, n_edges, counts);
    int nb = (N_NODES + 255) / 256;
    scan_local<<<nb, 256, 0, stream>>>(counts, N_NODES, offsets, blocksums);
    scan_block<<<1, 256, 0, stream>>>(blocksums, nb);
    scan_add<<<nb, 256, 0, stream>>>(offsets, cursor, blocksums, N_NODES, n_edges);
    scatter_kernel<<<(n_edges + 255) / 256, 256, 0, stream>>>(src, dst, n_edges, cursor, csr_src);

    wpack_prep<<<(N_LAYERS * 2 * 16384 + 255) / 256, 256, 0, stream>>>(W1, W2, wp);

    const int AGG_BLKS = (N_NODES + 3) / 4;
    for (int i = 0; i < N_LAYERS; ++i) {
        float* layer_out = out + (size_t)(1 + i) * N_NODES * DIM;
        if (i == 0) {
            for (int p = 0; p < 4; ++p)
                agg_pass_fp32<<<AGG_BLKS, 256, 0, stream>>>(
                    (const float4*)x, csr_src, offsets, p, h_hi_u, h_lo_u);
        } else {
            for (int p = 0; p < 2; ++p)
                agg_pass_bf<<<AGG_BLKS, 256, 0, stream>>>(
                    x_bf2, csr_src, offsets, p, h_hi_u, h_lo_u);
        }
        mlp_mfma<<<NBLK, 128, 0, stream>>>(
            h_hi, h_lo,
            (const short8*)(wp + (size_t)(i * 2) * 32768), b1 + (size_t)i * DIM,
            (const short8*)(wp + (size_t)(i * 2 + 1) * 32768), b2 + (size_t)i * DIM,
            layer_out, part_s, part_q);
        bn_reduce<<<256, 256, 0, stream>>>(part_s, part_q, bn_sum, bn_sq, NBLK);
        bn_apply<<<(N_NODES * DIM / 4 + 255) / 256, 256, 0, stream>>>(
            layer_out, bn_sum, bn_sq, gamma + (size_t)i * DIM, beta + (size_t)i * DIM,
            (i < N_LAYERS - 1) ? x_bf2 : (uint2*)nullptr,
            (i == N_LAYERS - 1) ? (float4*)out : (float4*)nullptr);
    }
}

// Round 13
// 533.117 us; speedup vs baseline: 1.1674x; 1.1674x over previous
//
#include <hip/hip_runtime.h>
#include <hip/hip_fp16.h>

#define N_NODES 50000
#define DIM 128
#define N_LAYERS 5
#define BN_EPS 1e-5f

typedef __attribute__((ext_vector_type(8))) short short8;
typedef __attribute__((ext_vector_type(4))) float f32x4;

__device__ __forceinline__ float bf2f(unsigned int u16) {
    union { unsigned int i; float f; } c; c.i = u16 << 16; return c.f;
}
__device__ __forceinline__ unsigned short f2bf(float f) {
    union { float f; unsigned int i; } c; c.f = f;
    unsigned int v = c.i + 0x7FFFu + ((c.i >> 16) & 1u);   // RNE
    return (unsigned short)(v >> 16);
}
__device__ __forceinline__ unsigned short f2h(float f) {
    __half h = __float2half(f);
    return *reinterpret_cast<unsigned short*>(&h);
}
__device__ __forceinline__ float h2f(unsigned short u) {
    __half h = *reinterpret_cast<__half*>(&u);
    return __half2float(h);
}

// ---------------- CSR build ----------------

__global__ void hist_kernel(const int* __restrict__ dst, int n_edges, int* __restrict__ counts) {
    int e = blockIdx.x * 256 + threadIdx.x;
    if (e < n_edges) atomicAdd(&counts[dst[e]], 1);
}

__global__ void scan_local(const int* __restrict__ counts, int n,
                           int* __restrict__ offsets, int* __restrict__ blocksums) {
    __shared__ int temp[256];
    int t = threadIdx.x;
    int i = blockIdx.x * 256 + t;
    int v = (i < n) ? counts[i] : 0;
    temp[t] = v;
    __syncthreads();
    for (int off = 1; off < 256; off <<= 1) {
        int add = (t >= off) ? temp[t - off] : 0;
        __syncthreads();
        temp[t] += add;
        __syncthreads();
    }
    if (i < n) offsets[i] = temp[t] - v;
    if (t == 255) blocksums[blockIdx.x] = temp[255];
}

__global__ void scan_block(int* __restrict__ blocksums, int nb) {
    __shared__ int temp[256];
    int t = threadIdx.x;
    int v = (t < nb) ? blocksums[t] : 0;
    temp[t] = v;
    __syncthreads();
    for (int off = 1; off < 256; off <<= 1) {
        int add = (t >= off) ? temp[t - off] : 0;
        __syncthreads();
        temp[t] += add;
        __syncthreads();
    }
    if (t < nb) blocksums[t] = temp[t] - v;
}

__global__ void scan_add(int* __restrict__ offsets, int* __restrict__ cursor,
                         const int* __restrict__ blocksums, int n, int n_edges) {
    int i = blockIdx.x * 256 + threadIdx.x;
    if (i < n) {
        int val = offsets[i] + blocksums[blockIdx.x];
        offsets[i] = val;
        cursor[i] = val;
    }
    if (i == 0) offsets[n] = n_edges;
}

__global__ void scatter_kernel(const int* __restrict__ src, const int* __restrict__ dst,
                               int n_edges, int* __restrict__ cursor, int* __restrict__ csr_src) {
    int e = blockIdx.x * 256 + threadIdx.x;
    if (e < n_edges) {
        int p = atomicAdd(&cursor[dst[e]], 1);
        csr_src[p] = src[e];
    }
}

// ---------------- prep ----------------

// pack W1/W2 (all layers) into MFMA B-fragment order, hi+lo bf16 planes.
__global__ void wpack_prep(const float* __restrict__ W1, const float* __restrict__ W2,
                           unsigned short* __restrict__ wp) {
    int idx = blockIdx.x * 256 + threadIdx.x;
    if (idx >= N_LAYERS * 2 * 16384) return;
    int j    = idx & 7;
    int lane = (idx >> 3) & 63;
    int nt   = (idx >> 9) & 7;
    int ks   = (idx >> 12) & 3;
    int mat  = (idx >> 14) & 1;
    int lay  = idx >> 15;
    int l15 = lane & 15, l4 = lane >> 4;
    int col = nt * 16 + l15;
    int kp = ks * 32 + l4 * 8 + j;
    int k = mat ? ((kp & 7) * 16 + (kp >> 3)) : kp;
    const float* W = mat ? W2 : W1;
    float w = W[((size_t)lay * 128 + k) * 128 + col];
    unsigned short hi = f2bf(w);
    unsigned short lo = f2bf(w - bf2f(hi));
    size_t base = (size_t)(lay * 2 + mat) * 32768;
    size_t inner = (size_t)((ks * 8 + nt) * 64 + lane) * 8 + j;
    wp[base + inner] = hi;
    wp[base + 16384 + inner] = lo;
}

// x (fp32) -> fp16 table (4 halves per uint2)
__global__ void convert_x_f16(const float4* __restrict__ x, uint2* __restrict__ xh, int n4) {
    int i = blockIdx.x * 256 + threadIdx.x;
    if (i >= n4) return;
    float4 v = x[i];
    uint2 o;
    o.x = (unsigned int)f2h(v.x) | ((unsigned int)f2h(v.y) << 16);
    o.y = (unsigned int)f2h(v.z) | ((unsigned int)f2h(v.w) << 16);
    xh[i] = o;
}

// ---------------- fused aggregation + BN-affine fold ----------------
// Gathers fp16 RAW features (pre-BN), applies the previous layer's BN affine
// to the SUM (BN commutes with aggregation: sum(A*h+B) = A*sum(h) + B*cnt),
// emits hi/lo bf16 planes for the MFMA MLP, and writes the previous layer's
// normalized fp32 output xs[i-1] from the self term.
// Quarter-wave gathers: 16 lanes x uint4 (8 halves) per 256B row, 4 edges per
// instruction, depth-8 = 32 edges in flight per wave.
__global__ void agg_f16(const uint4* __restrict__ tbl4, const int* __restrict__ csr_src,
                        const int* __restrict__ offsets,
                        const float* __restrict__ bn_sum, const float* __restrict__ bn_sq,
                        const float* __restrict__ gamma, const float* __restrict__ beta,
                        float* __restrict__ xs_out,
                        unsigned int* __restrict__ h_hi_u, unsigned int* __restrict__ h_lo_u) {
    int wave = threadIdx.x >> 6;
    int l = threadIdx.x & 63;
    int node = blockIdx.x * 4 + wave;
    if (node >= N_NODES) return;
    int g = l >> 4;          // edge slot 0..3
    int d = l & 15;          // uint4 chunk: channels d*8 .. d*8+7
    int beg = offsets[node], end = offsets[node + 1];

    float self[8];
    float a[8];
#pragma unroll
    for (int j = 0; j < 8; ++j) { a[j] = 0.0f; self[j] = 0.0f; }
    if (g == 0) {
        uint4 u = tbl4[(size_t)node * 16 + d];   // self term
        self[0] = h2f(u.x & 0xFFFFu); self[1] = h2f(u.x >> 16);
        self[2] = h2f(u.y & 0xFFFFu); self[3] = h2f(u.y >> 16);
        self[4] = h2f(u.z & 0xFFFFu); self[5] = h2f(u.z >> 16);
        self[6] = h2f(u.w & 0xFFFFu); self[7] = h2f(u.w >> 16);
#pragma unroll
        for (int j = 0; j < 8; ++j) a[j] = self[j];
    }

    for (int e = beg; e < end; e += 32) {
        int s[8];
#pragma unroll
        for (int i = 0; i < 8; ++i) s[i] = csr_src[min(e + 4 * i + g, end - 1)];
        uint4 v[8];
#pragma unroll
        for (int i = 0; i < 8; ++i) v[i] = tbl4[(size_t)s[i] * 16 + d];
#pragma unroll
        for (int i = 0; i < 8; ++i) {
            float w = (e + 4 * i + g < end) ? 1.0f : 0.0f;   // mask tail
            a[0] = fmaf(h2f(v[i].x & 0xFFFFu), w, a[0]);
            a[1] = fmaf(h2f(v[i].x >> 16),     w, a[1]);
            a[2] = fmaf(h2f(v[i].y & 0xFFFFu), w, a[2]);
            a[3] = fmaf(h2f(v[i].y >> 16),     w, a[3]);
            a[4] = fmaf(h2f(v[i].z & 0xFFFFu), w, a[4]);
            a[5] = fmaf(h2f(v[i].z >> 16),     w, a[5]);
            a[6] = fmaf(h2f(v[i].w & 0xFFFFu), w, a[6]);
            a[7] = fmaf(h2f(v[i].w >> 16),     w, a[7]);
        }
    }

    // reduce across the 4 edge slots (lanes l, l^16, l^32, l^48 share d)
#pragma unroll
    for (int j = 0; j < 8; ++j) {
        a[j] += __shfl_xor(a[j], 16);
        a[j] += __shfl_xor(a[j], 32);
    }

    // BN-affine fold (prev layer): z = A*sum + B*cnt ; xs = A*self + B
    if (bn_sum) {
        const float invN = 1.0f / (float)N_NODES;
        float cnt = (float)(end - beg + 1);
#pragma unroll
        for (int j = 0; j < 8; ++j) {
            int c = d * 8 + j;
            float mean = bn_sum[c] * invN;
            float var = fmaxf(bn_sq[c] * invN - mean * mean, 0.0f);
            float inv = rsqrtf(var + BN_EPS);
            float A = gamma[c] * inv;
            float B = beta[c] - mean * A;
            a[j] = A * a[j] + B * cnt;
            self[j] = A * self[j] + B;
        }
    }

    unsigned short h[8];
#pragma unroll
    for (int j = 0; j < 8; ++j) h[j] = f2bf(a[j]);
    if (g == 0) {
        uint4 hv;
        hv.x = (unsigned int)h[0] | ((unsigned int)h[1] << 16);
        hv.y = (unsigned int)h[2] | ((unsigned int)h[3] << 16);
        hv.z = (unsigned int)h[4] | ((unsigned int)h[5] << 16);
        hv.w = (unsigned int)h[6] | ((unsigned int)h[7] << 16);
        ((uint4*)h_hi_u)[(size_t)node * 16 + d] = hv;
        if (xs_out) {
            float4 o0 = make_float4(self[0], self[1], self[2], self[3]);
            float4 o1 = make_float4(self[4], self[5], self[6], self[7]);
            ((float4*)xs_out)[(size_t)node * 32 + d * 2]     = o0;
            ((float4*)xs_out)[(size_t)node * 32 + d * 2 + 1] = o1;
        }
    } else if (g == 1) {
        unsigned short lo[8];
#pragma unroll
        for (int j = 0; j < 8; ++j) lo[j] = f2bf(a[j] - bf2f(h[j]));
        uint4 lv;
        lv.x = (unsigned int)lo[0] | ((unsigned int)lo[1] << 16);
        lv.y = (unsigned int)lo[2] | ((unsigned int)lo[3] << 16);
        lv.z = (unsigned int)lo[4] | ((unsigned int)lo[5] << 16);
        lv.w = (unsigned int)lo[6] | ((unsigned int)lo[7] << 16);
        ((uint4*)h_lo_u)[(size_t)node * 16 + d] = lv;
    }
}

// fused MFMA MLP (bf16x2 split, 3-product): ReLU(h@W1+b1)@W2+b2 -> ReLU
// -> raw fp16 + per-block BN partials (stats on fp32 values)
__global__ __launch_bounds__(128) void mlp_mfma(
        const unsigned short* __restrict__ h_hi, const unsigned short* __restrict__ h_lo,
        const short8* __restrict__ wp1, const float* __restrict__ b1,
        const short8* __restrict__ wp2, const float* __restrict__ b2,
        unsigned short* __restrict__ raw_h,
        float* __restrict__ part_s, float* __restrict__ part_q) {
    __shared__ unsigned short mid_hi[2][2][16][128];   // [wave][m][row][kp], XOR-swizzled
    __shared__ unsigned short mid_lo[2][2][16][128];
    __shared__ float red_s[2][128], red_q[2][128];
    int t = threadIdx.x, wave = t >> 6, l = t & 63;
    int l15 = l & 15, l4 = l >> 4;
    int row_base = blockIdx.x * 64 + wave * 32;

    int r0 = row_base + l15, r1 = r0 + 16;
    int cr0 = min(r0, N_NODES - 1), cr1 = min(r1, N_NODES - 1);
    const short8* ah0p = (const short8*)(h_hi + (size_t)cr0 * 128);
    const short8* ah1p = (const short8*)(h_hi + (size_t)cr1 * 128);
    const short8* al0p = (const short8*)(h_lo + (size_t)cr0 * 128);
    const short8* al1p = (const short8*)(h_lo + (size_t)cr1 * 128);

    const short8* wp1l = wp1 + 2048;   // lo plane
    const short8* wp2l = wp2 + 2048;

    f32x4 acc[2][8];
#pragma unroll
    for (int m = 0; m < 2; ++m)
#pragma unroll
        for (int nt = 0; nt < 8; ++nt) acc[m][nt] = (f32x4)0.0f;

#pragma unroll
    for (int ks = 0; ks < 4; ++ks) {
        short8 ah0 = ah0p[ks * 4 + l4];
        short8 ah1 = ah1p[ks * 4 + l4];
        short8 al0 = al0p[ks * 4 + l4];
        short8 al1 = al1p[ks * 4 + l4];
#pragma unroll
        for (int nt = 0; nt < 8; ++nt) {
            short8 whi = wp1[(ks * 8 + nt) * 64 + l];
            short8 wlo = wp1l[(ks * 8 + nt) * 64 + l];
            acc[0][nt] = __builtin_amdgcn_mfma_f32_16x16x32_bf16(ah0, whi, acc[0][nt], 0, 0, 0);
            acc[0][nt] = __builtin_amdgcn_mfma_f32_16x16x32_bf16(al0, whi, acc[0][nt], 0, 0, 0);
            acc[0][nt] = __builtin_amdgcn_mfma_f32_16x16x32_bf16(ah0, wlo, acc[0][nt], 0, 0, 0);
            acc[1][nt] = __builtin_amdgcn_mfma_f32_16x16x32_bf16(ah1, whi, acc[1][nt], 0, 0, 0);
            acc[1][nt] = __builtin_amdgcn_mfma_f32_16x16x32_bf16(al1, whi, acc[1][nt], 0, 0, 0);
            acc[1][nt] = __builtin_amdgcn_mfma_f32_16x16x32_bf16(ah1, wlo, acc[1][nt], 0, 0, 0);
        }
    }

    float b1v[8];
#pragma unroll
    for (int nt = 0; nt < 8; ++nt) b1v[nt] = b1[nt * 16 + l15];

#pragma unroll
    for (int m = 0; m < 2; ++m) {
#pragma unroll
        for (int rr = 0; rr < 4; ++rr) {
            int row = l4 * 4 + rr;
            short8 ph, pl;
#pragma unroll
            for (int nt = 0; nt < 8; ++nt) {
                float v = fmaxf(acc[m][nt][rr] + b1v[nt], 0.0f);
                unsigned short hv = f2bf(v);
                ph[nt] = (short)hv;
                pl[nt] = (short)f2bf(v - bf2f(hv));
            }
            int off = (l15 * 16) ^ ((row & 7) << 4);
            *(short8*)((char*)&mid_hi[wave][m][row][0] + off) = ph;
            *(short8*)((char*)&mid_lo[wave][m][row][0] + off) = pl;
        }
    }
    __syncthreads();

    f32x4 acc2[2][8];
#pragma unroll
    for (int m = 0; m < 2; ++m)
#pragma unroll
        for (int nt = 0; nt < 8; ++nt) acc2[m][nt] = (f32x4)0.0f;

#pragma unroll
    for (int ks = 0; ks < 4; ++ks) {
        int off = (ks * 64 + l4 * 16) ^ ((l15 & 7) << 4);
        short8 ah0 = *(const short8*)((char*)&mid_hi[wave][0][l15][0] + off);
        short8 ah1 = *(const short8*)((char*)&mid_hi[wave][1][l15][0] + off);
        short8 al0 = *(const short8*)((char*)&mid_lo[wave][0][l15][0] + off);
        short8 al1 = *(const short8*)((char*)&mid_lo[wave][1][l15][0] + off);
#pragma unroll
        for (int nt = 0; nt < 8; ++nt) {
            short8 whi = wp2[(ks * 8 + nt) * 64 + l];
            short8 wlo = wp2l[(ks * 8 + nt) * 64 + l];
            acc2[0][nt] = __builtin_amdgcn_mfma_f32_16x16x32_bf16(ah0, whi, acc2[0][nt], 0, 0, 0);
            acc2[0][nt] = __builtin_amdgcn_mfma_f32_16x16x32_bf16(al0, whi, acc2[0][nt], 0, 0, 0);
            acc2[0][nt] = __builtin_amdgcn_mfma_f32_16x16x32_bf16(ah0, wlo, acc2[0][nt], 0, 0, 0);
            acc2[1][nt] = __builtin_amdgcn_mfma_f32_16x16x32_bf16(ah1, whi, acc2[1][nt], 0, 0, 0);
            acc2[1][nt] = __builtin_amdgcn_mfma_f32_16x16x32_bf16(al1, whi, acc2[1][nt], 0, 0, 0);
            acc2[1][nt] = __builtin_amdgcn_mfma_f32_16x16x32_bf16(ah1, wlo, acc2[1][nt], 0, 0, 0);
        }
    }

    float b2v[8];
#pragma unroll
    for (int nt = 0; nt < 8; ++nt) b2v[nt] = b2[nt * 16 + l15];

    float s[8], q[8];
#pragma unroll
    for (int nt = 0; nt < 8; ++nt) { s[nt] = 0.0f; q[nt] = 0.0f; }

#pragma unroll
    for (int m = 0; m < 2; ++m) {
#pragma unroll
        for (int rr = 0; rr < 4; ++rr) {
            int rg = row_base + m * 16 + l4 * 4 + rr;
            bool ok = rg < N_NODES;
#pragma unroll
            for (int nt = 0; nt < 8; ++nt) {
                float v = fmaxf(acc2[m][nt][rr] + b2v[nt], 0.0f);   // outer ReLU
                if (ok) {
                    raw_h[(size_t)rg * 128 + nt * 16 + l15] = f2h(v);
                    s[nt] += v;
                    q[nt] += v * v;
                }
            }
        }
    }
#pragma unroll
    for (int nt = 0; nt < 8; ++nt) {
        s[nt] += __shfl_xor(s[nt], 16); s[nt] += __shfl_xor(s[nt], 32);
        q[nt] += __shfl_xor(q[nt], 16); q[nt] += __shfl_xor(q[nt], 32);
    }
    if (l4 == 0) {
#pragma unroll
        for (int nt = 0; nt < 8; ++nt) {
            red_s[wave][nt * 16 + l15] = s[nt];
            red_q[wave][nt * 16 + l15] = q[nt];
        }
    }
    __syncthreads();
    if (t < 128) {
        part_s[blockIdx.x * 128 + t] = red_s[0][t] + red_s[1][t];
        part_q[blockIdx.x * 128 + t] = red_q[0][t] + red_q[1][t];
    }
}

// 256 blocks: block b reduces channel (b&127) of (b>>7 ? part_q : part_s)
__global__ __launch_bounds__(256) void bn_reduce(
        const float* __restrict__ part_s, const float* __restrict__ part_q,
        float* __restrict__ bn_sum, float* __restrict__ bn_sq, int nparts) {
    __shared__ float red[256];
    int c = blockIdx.x & 127;
    const float* src = (blockIdx.x >> 7) ? part_q : part_s;
    float* dst = (blockIdx.x >> 7) ? bn_sq : bn_sum;
    float a = 0.0f;
    for (int p = threadIdx.x; p < nparts; p += 256) a += src[p * 128 + c];
    red[threadIdx.x] = a;
    __syncthreads();
    for (int s = 128; s > 0; s >>= 1) {
        if (threadIdx.x < s) red[threadIdx.x] += red[threadIdx.x + s];
        __syncthreads();
    }
    if (threadIdx.x == 0) dst[c] = red[0];
}

// final layer: read fp16 raw, normalize, write xs[4] fp32 + final-h fp32
__global__ void bn_apply_last(const uint2* __restrict__ hraw,
                              float4* __restrict__ xs, float4* __restrict__ fin,
                              const float* __restrict__ bn_sum, const float* __restrict__ bn_sq,
                              const float* __restrict__ gamma, const float* __restrict__ beta) {
    int i4 = blockIdx.x * 256 + threadIdx.x;
    if (i4 >= N_NODES * DIM / 4) return;
    uint2 u = hraw[i4];
    float vv[4] = { h2f(u.x & 0xFFFFu), h2f(u.x >> 16),
                    h2f(u.y & 0xFFFFu), h2f(u.y >> 16) };
    int c0 = (i4 & 31) * 4;
    const float invN = 1.0f / (float)N_NODES;
    float4 o;
    float* op = (float*)&o;
#pragma unroll
    for (int j = 0; j < 4; ++j) {
        int c = c0 + j;
        float mean = bn_sum[c] * invN;
        float var = fmaxf(bn_sq[c] * invN - mean * mean, 0.0f);
        float inv = rsqrtf(var + BN_EPS);
        op[j] = (vv[j] - mean) * inv * gamma[c] + beta[c];
    }
    xs[i4] = o;
    fin[i4] = o;
}

// ---------------- launch ----------------

extern "C" void kernel_launch(void* const* d_in, const int* in_sizes, int n_in,
                              void* d_out, int out_size, void* d_ws, size_t ws_size,
                              hipStream_t stream) {
    const float* x     = (const float*)d_in[0];
    const int*   eidx  = (const int*)d_in[1];
    const float* W1    = (const float*)d_in[3];
    const float* b1    = (const float*)d_in[4];
    const float* W2    = (const float*)d_in[5];
    const float* b2    = (const float*)d_in[6];
    const float* gamma = (const float*)d_in[7];
    const float* beta  = (const float*)d_in[8];

    int n_edges = in_sizes[1] / 2;
    const int* src = eidx;
    const int* dst = eidx + n_edges;

    const int NBLK = (N_NODES + 63) / 64;    // 782 mlp blocks

    int* counts    = (int*)d_ws;                       // 50000
    int* offsets   = counts + N_NODES;                 // 50001
    int* cursor    = offsets + N_NODES + 1;            // 50000
    int* blocksums = cursor + N_NODES;                 // 256
    int* csr_src   = blocksums + 256;                  // n_edges
    float* part_s  = (float*)(csr_src + n_edges);      // NBLK*128
    float* part_q  = part_s + NBLK * 128;              // NBLK*128
    float* bn_sum  = part_q + NBLK * 128;              // 128
    float* bn_sq   = bn_sum + DIM;                     // 128
    size_t wp_off = (((size_t)(bn_sq + DIM) - (size_t)d_ws) + 15) & ~(size_t)15;
    unsigned short* wp = (unsigned short*)((char*)d_ws + wp_off);   // 5*2*32768 bf16 (hi+lo)
    // shared fp16 node-feature table (x for layer 0, then raw(i) after mlp(i))
    size_t tb_off = (wp_off + (size_t)N_LAYERS * 2 * 32768 * 2 + 15) & ~(size_t)15;
    unsigned short* tbl = (unsigned short*)((char*)d_ws + tb_off);  // [N][128] halves = 12.8 MB

    float* out = (float*)d_out;
    // slot 0 doubles as bf16 hi/lo plane scratch until bn_apply_last overwrites it
    unsigned int* h_hi_u = (unsigned int*)d_out;                    // [N][64] uints
    unsigned int* h_lo_u = h_hi_u + (size_t)N_NODES * 64;
    const unsigned short* h_hi = (const unsigned short*)h_hi_u;
    const unsigned short* h_lo = (const unsigned short*)h_lo_u;

    // CSR build
    hipMemsetAsync(counts, 0, N_NODES * sizeof(int), stream);
    hist_kernel<<<(n_edges + 255) / 256, 256, 0, stream>>>(dst, n_edges, counts);
    int nb = (N_NODES + 255) / 256;
    scan_local<<<nb, 256, 0, stream>>>(counts, N_NODES, offsets, blocksums);
    scan_block<<<1, 256, 0, stream>>>(blocksums, nb);
    scan_add<<<nb, 256, 0, stream>>>(offsets, cursor, blocksums, N_NODES, n_edges);
    scatter_kernel<<<(n_edges + 255) / 256, 256, 0, stream>>>(src, dst, n_edges, cursor, csr_src);

    wpack_prep<<<(N_LAYERS * 2 * 16384 + 255) / 256, 256, 0, stream>>>(W1, W2, wp);
    convert_x_f16<<<(N_NODES * DIM / 4 + 255) / 256, 256, 0, stream>>>(
        (const float4*)x, (uint2*)tbl, N_NODES * DIM / 4);

    const int AGG_BLKS = (N_NODES + 3) / 4;
    for (int i = 0; i < N_LAYERS; ++i) {
        // agg(i): gather tbl (= x for i==0, raw(i-1) otherwise); for i>0 apply
        // layer-(i-1) BN affine to the sum and emit xs[i-1] from the self term.
        agg_f16<<<AGG_BLKS, 256, 0, stream>>>(
            (const uint4*)tbl, csr_src, offsets,
            (i > 0) ? bn_sum : (const float*)nullptr, bn_sq,
            (i > 0) ? gamma + (size_t)(i - 1) * DIM : (const float*)nullptr,
            (i > 0) ? beta + (size_t)(i - 1) * DIM : (const float*)nullptr,
            (i > 0) ? out + (size_t)i * N_NODES * DIM : (float*)nullptr,
            h_hi_u, h_lo_u);
        // mlp(i): GEMMs, overwrite tbl with raw(i) fp16, emit BN partials
        mlp_mfma<<<NBLK, 128, 0, stream>>>(
            h_hi, h_lo,
            (const short8*)(wp + (size_t)(i * 2) * 32768), b1 + (size_t)i * DIM,
            (const short8*)(wp + (size_t)(i * 2 + 1) * 32768), b2 + (size_t)i * DIM,
            tbl, part_s, part_q);
        bn_reduce<<<256, 256, 0, stream>>>(part_s, part_q, bn_sum, bn_sq, NBLK);
    }
    bn_apply_last<<<(N_NODES * DIM / 4 + 255) / 256, 256, 0, stream>>>(
        (const uint2*)tbl,
        (float4*)(out + (size_t)N_LAYERS * N_NODES * DIM), (float4*)out,
        bn_sum, bn_sq, gamma + (size_t)(N_LAYERS - 1) * DIM,
        beta + (size_t)(N_LAYERS - 1) * DIM);
}

// Round 14
// 520.740 us; speedup vs baseline: 1.1952x; 1.0238x over previous
//
#include <hip/hip_runtime.h>
#include <hip/hip_fp16.h>

#define N_NODES 50000
#define DIM 128
#define N_LAYERS 5
#define BN_EPS 1e-5f

typedef __attribute__((ext_vector_type(8))) short short8;
typedef __attribute__((ext_vector_type(4))) float f32x4;

__device__ __forceinline__ float bf2f(unsigned int u16) {
    union { unsigned int i; float f; } c; c.i = u16 << 16; return c.f;
}
__device__ __forceinline__ unsigned short f2bf(float f) {
    union { float f; unsigned int i; } c; c.f = f;
    unsigned int v = c.i + 0x7FFFu + ((c.i >> 16) & 1u);   // RNE
    return (unsigned short)(v >> 16);
}
__device__ __forceinline__ unsigned short f2h(float f) {
    __half h = __float2half(f);
    return *reinterpret_cast<unsigned short*>(&h);
}
__device__ __forceinline__ float h2f(unsigned short u) {
    __half h = *reinterpret_cast<__half*>(&u);
    return __half2float(h);
}

// split 8 fp16 values into bf16 hi + exact residual lo (fits: 8+3 >= 11 bits)
__device__ __forceinline__ void h8_split(uint4 u, short8& hi, short8& lo) {
    float f[8] = { h2f(u.x & 0xFFFFu), h2f(u.x >> 16),
                   h2f(u.y & 0xFFFFu), h2f(u.y >> 16),
                   h2f(u.z & 0xFFFFu), h2f(u.z >> 16),
                   h2f(u.w & 0xFFFFu), h2f(u.w >> 16) };
#pragma unroll
    for (int j = 0; j < 8; ++j) {
        unsigned short hv = f2bf(f[j]);
        hi[j] = (short)hv;
        lo[j] = (short)f2bf(f[j] - bf2f(hv));
    }
}

// ---------------- CSR build ----------------

__global__ void hist_kernel(const int* __restrict__ dst, int n_edges, int* __restrict__ counts) {
    int e = blockIdx.x * 256 + threadIdx.x;
    if (e < n_edges) atomicAdd(&counts[dst[e]], 1);
}

__global__ void scan_local(const int* __restrict__ counts, int n,
                           int* __restrict__ offsets, int* __restrict__ blocksums) {
    __shared__ int temp[256];
    int t = threadIdx.x;
    int i = blockIdx.x * 256 + t;
    int v = (i < n) ? counts[i] : 0;
    temp[t] = v;
    __syncthreads();
    for (int off = 1; off < 256; off <<= 1) {
        int add = (t >= off) ? temp[t - off] : 0;
        __syncthreads();
        temp[t] += add;
        __syncthreads();
    }
    if (i < n) offsets[i] = temp[t] - v;
    if (t == 255) blocksums[blockIdx.x] = temp[255];
}

__global__ void scan_block(int* __restrict__ blocksums, int nb) {
    __shared__ int temp[256];
    int t = threadIdx.x;
    int v = (t < nb) ? blocksums[t] : 0;
    temp[t] = v;
    __syncthreads();
    for (int off = 1; off < 256; off <<= 1) {
        int add = (t >= off) ? temp[t - off] : 0;
        __syncthreads();
        temp[t] += add;
        __syncthreads();
    }
    if (t < nb) blocksums[t] = temp[t] - v;
}

__global__ void scan_add(int* __restrict__ offsets, int* __restrict__ cursor,
                         const int* __restrict__ blocksums, int n, int n_edges) {
    int i = blockIdx.x * 256 + threadIdx.x;
    if (i < n) {
        int val = offsets[i] + blocksums[blockIdx.x];
        offsets[i] = val;
        cursor[i] = val;
    }
    if (i == 0) offsets[n] = n_edges;
}

__global__ void scatter_kernel(const int* __restrict__ src, const int* __restrict__ dst,
                               int n_edges, int* __restrict__ cursor, int* __restrict__ csr_src) {
    int e = blockIdx.x * 256 + threadIdx.x;
    if (e < n_edges) {
        int p = atomicAdd(&cursor[dst[e]], 1);
        csr_src[p] = src[e];
    }
}

// ---------------- prep ----------------

// pack W1/W2 (all layers) into MFMA B-fragment order, hi+lo bf16 planes.
__global__ void wpack_prep(const float* __restrict__ W1, const float* __restrict__ W2,
                           unsigned short* __restrict__ wp) {
    int idx = blockIdx.x * 256 + threadIdx.x;
    if (idx >= N_LAYERS * 2 * 16384) return;
    int j    = idx & 7;
    int lane = (idx >> 3) & 63;
    int nt   = (idx >> 9) & 7;
    int ks   = (idx >> 12) & 3;
    int mat  = (idx >> 14) & 1;
    int lay  = idx >> 15;
    int l15 = lane & 15, l4 = lane >> 4;
    int col = nt * 16 + l15;
    int kp = ks * 32 + l4 * 8 + j;
    int k = mat ? ((kp & 7) * 16 + (kp >> 3)) : kp;
    const float* W = mat ? W2 : W1;
    float w = W[((size_t)lay * 128 + k) * 128 + col];
    unsigned short hi = f2bf(w);
    unsigned short lo = f2bf(w - bf2f(hi));
    size_t base = (size_t)(lay * 2 + mat) * 32768;
    size_t inner = (size_t)((ks * 8 + nt) * 64 + lane) * 8 + j;
    wp[base + inner] = hi;
    wp[base + 16384 + inner] = lo;
}

// x (fp32) -> fp16 table
__global__ void convert_x_f16(const float4* __restrict__ x, uint2* __restrict__ xh, int n4) {
    int i = blockIdx.x * 256 + threadIdx.x;
    if (i >= n4) return;
    float4 v = x[i];
    uint2 o;
    o.x = (unsigned int)f2h(v.x) | ((unsigned int)f2h(v.y) << 16);
    o.y = (unsigned int)f2h(v.z) | ((unsigned int)f2h(v.w) << 16);
    xh[i] = o;
}

// ---------------- fused aggregation + BN-affine fold ----------------
// Gathers fp16 RAW features (pre-BN), applies the previous layer's BN affine
// to the SUM (BN commutes: sum(A*h+B) = A*sum(h) + B*cnt), writes the fp16
// aggregated-sum table for the MLP, and emits xs[i-1] from the self term.
// Quarter-wave gathers: 16 lanes x uint4 (8 halves) per 256B row, 4 edges per
// instruction, depth-8 = 32 edges in flight per wave.
__global__ void agg_f16(const uint4* __restrict__ tbl4, const int* __restrict__ csr_src,
                        const int* __restrict__ offsets,
                        const float* __restrict__ bn_sum, const float* __restrict__ bn_sq,
                        const float* __restrict__ gamma, const float* __restrict__ beta,
                        float* __restrict__ xs_out,
                        uint4* __restrict__ hsum4) {
    int wave = threadIdx.x >> 6;
    int l = threadIdx.x & 63;
    int node = blockIdx.x * 4 + wave;
    if (node >= N_NODES) return;
    int g = l >> 4;          // edge slot 0..3
    int d = l & 15;          // uint4 chunk: channels d*8 .. d*8+7
    int beg = offsets[node], end = offsets[node + 1];

    float self[8];
    float a[8];
#pragma unroll
    for (int j = 0; j < 8; ++j) { a[j] = 0.0f; self[j] = 0.0f; }
    if (g == 0) {
        uint4 u = tbl4[(size_t)node * 16 + d];   // self term
        self[0] = h2f(u.x & 0xFFFFu); self[1] = h2f(u.x >> 16);
        self[2] = h2f(u.y & 0xFFFFu); self[3] = h2f(u.y >> 16);
        self[4] = h2f(u.z & 0xFFFFu); self[5] = h2f(u.z >> 16);
        self[6] = h2f(u.w & 0xFFFFu); self[7] = h2f(u.w >> 16);
#pragma unroll
        for (int j = 0; j < 8; ++j) a[j] = self[j];
    }

    for (int e = beg; e < end; e += 32) {
        int s[8];
#pragma unroll
        for (int i = 0; i < 8; ++i) s[i] = csr_src[min(e + 4 * i + g, end - 1)];
        uint4 v[8];
#pragma unroll
        for (int i = 0; i < 8; ++i) v[i] = tbl4[(size_t)s[i] * 16 + d];
#pragma unroll
        for (int i = 0; i < 8; ++i) {
            float w = (e + 4 * i + g < end) ? 1.0f : 0.0f;   // mask tail
            a[0] = fmaf(h2f(v[i].x & 0xFFFFu), w, a[0]);
            a[1] = fmaf(h2f(v[i].x >> 16),     w, a[1]);
            a[2] = fmaf(h2f(v[i].y & 0xFFFFu), w, a[2]);
            a[3] = fmaf(h2f(v[i].y >> 16),     w, a[3]);
            a[4] = fmaf(h2f(v[i].z & 0xFFFFu), w, a[4]);
            a[5] = fmaf(h2f(v[i].z >> 16),     w, a[5]);
            a[6] = fmaf(h2f(v[i].w & 0xFFFFu), w, a[6]);
            a[7] = fmaf(h2f(v[i].w >> 16),     w, a[7]);
        }
    }

    // reduce across the 4 edge slots (lanes l, l^16, l^32, l^48 share d)
#pragma unroll
    for (int j = 0; j < 8; ++j) {
        a[j] += __shfl_xor(a[j], 16);
        a[j] += __shfl_xor(a[j], 32);
    }

    if (g != 0) return;

    // BN-affine fold (prev layer): z = A*sum + B*cnt ; xs = A*self + B
    if (bn_sum) {
        const float invN = 1.0f / (float)N_NODES;
        float cnt = (float)(end - beg + 1);
#pragma unroll
        for (int j = 0; j < 8; ++j) {
            int c = d * 8 + j;
            float mean = bn_sum[c] * invN;
            float var = fmaxf(bn_sq[c] * invN - mean * mean, 0.0f);
            float inv = rsqrtf(var + BN_EPS);
            float A = gamma[c] * inv;
            float B = beta[c] - mean * A;
            a[j] = A * a[j] + B * cnt;
            self[j] = A * self[j] + B;
        }
        if (xs_out) {
            float4 o0 = make_float4(self[0], self[1], self[2], self[3]);
            float4 o1 = make_float4(self[4], self[5], self[6], self[7]);
            ((float4*)xs_out)[(size_t)node * 32 + d * 2]     = o0;
            ((float4*)xs_out)[(size_t)node * 32 + d * 2 + 1] = o1;
        }
    }

    uint4 o;
    o.x = (unsigned int)f2h(a[0]) | ((unsigned int)f2h(a[1]) << 16);
    o.y = (unsigned int)f2h(a[2]) | ((unsigned int)f2h(a[3]) << 16);
    o.z = (unsigned int)f2h(a[4]) | ((unsigned int)f2h(a[5]) << 16);
    o.w = (unsigned int)f2h(a[6]) | ((unsigned int)f2h(a[7]) << 16);
    hsum4[(size_t)node * 16 + d] = o;
}

// fused MFMA MLP (bf16x2 split, 3-product): ReLU(h@W1+b1)@W2+b2 -> ReLU
// -> raw fp16 + per-block BN partials. A-operand read as fp16 sums and
// split hi/lo in-register (exact representation of the fp16 value).
__global__ __launch_bounds__(128) void mlp_mfma(
        const uint4* __restrict__ hsum4,
        const short8* __restrict__ wp1, const float* __restrict__ b1,
        const short8* __restrict__ wp2, const float* __restrict__ b2,
        unsigned short* __restrict__ raw_h,
        float* __restrict__ part_s, float* __restrict__ part_q) {
    __shared__ unsigned short mid_hi[2][2][16][128];   // [wave][m][row][kp], XOR-swizzled
    __shared__ unsigned short mid_lo[2][2][16][128];
    __shared__ float red_s[2][128], red_q[2][128];
    int t = threadIdx.x, wave = t >> 6, l = t & 63;
    int l15 = l & 15, l4 = l >> 4;
    int row_base = blockIdx.x * 64 + wave * 32;

    int r0 = row_base + l15, r1 = r0 + 16;
    int cr0 = min(r0, N_NODES - 1), cr1 = min(r1, N_NODES - 1);
    const uint4* a0p = hsum4 + (size_t)cr0 * 16;
    const uint4* a1p = hsum4 + (size_t)cr1 * 16;

    const short8* wp1l = wp1 + 2048;   // lo plane
    const short8* wp2l = wp2 + 2048;

    f32x4 acc[2][8];
#pragma unroll
    for (int m = 0; m < 2; ++m)
#pragma unroll
        for (int nt = 0; nt < 8; ++nt) acc[m][nt] = (f32x4)0.0f;

#pragma unroll
    for (int ks = 0; ks < 4; ++ks) {
        short8 ah0, al0, ah1, al1;
        h8_split(a0p[ks * 4 + l4], ah0, al0);
        h8_split(a1p[ks * 4 + l4], ah1, al1);
#pragma unroll
        for (int nt = 0; nt < 8; ++nt) {
            short8 whi = wp1[(ks * 8 + nt) * 64 + l];
            short8 wlo = wp1l[(ks * 8 + nt) * 64 + l];
            acc[0][nt] = __builtin_amdgcn_mfma_f32_16x16x32_bf16(ah0, whi, acc[0][nt], 0, 0, 0);
            acc[0][nt] = __builtin_amdgcn_mfma_f32_16x16x32_bf16(al0, whi, acc[0][nt], 0, 0, 0);
            acc[0][nt] = __builtin_amdgcn_mfma_f32_16x16x32_bf16(ah0, wlo, acc[0][nt], 0, 0, 0);
            acc[1][nt] = __builtin_amdgcn_mfma_f32_16x16x32_bf16(ah1, whi, acc[1][nt], 0, 0, 0);
            acc[1][nt] = __builtin_amdgcn_mfma_f32_16x16x32_bf16(al1, whi, acc[1][nt], 0, 0, 0);
            acc[1][nt] = __builtin_amdgcn_mfma_f32_16x16x32_bf16(ah1, wlo, acc[1][nt], 0, 0, 0);
        }
    }

    float b1v[8];
#pragma unroll
    for (int nt = 0; nt < 8; ++nt) b1v[nt] = b1[nt * 16 + l15];

#pragma unroll
    for (int m = 0; m < 2; ++m) {
#pragma unroll
        for (int rr = 0; rr < 4; ++rr) {
            int row = l4 * 4 + rr;
            short8 ph, pl;
#pragma unroll
            for (int nt = 0; nt < 8; ++nt) {
                float v = fmaxf(acc[m][nt][rr] + b1v[nt], 0.0f);
                unsigned short hv = f2bf(v);
                ph[nt] = (short)hv;
                pl[nt] = (short)f2bf(v - bf2f(hv));
            }
            int off = (l15 * 16) ^ ((row & 7) << 4);
            *(short8*)((char*)&mid_hi[wave][m][row][0] + off) = ph;
            *(short8*)((char*)&mid_lo[wave][m][row][0] + off) = pl;
        }
    }
    __syncthreads();

    f32x4 acc2[2][8];
#pragma unroll
    for (int m = 0; m < 2; ++m)
#pragma unroll
        for (int nt = 0; nt < 8; ++nt) acc2[m][nt] = (f32x4)0.0f;

#pragma unroll
    for (int ks = 0; ks < 4; ++ks) {
        int off = (ks * 64 + l4 * 16) ^ ((l15 & 7) << 4);
        short8 ah0 = *(const short8*)((char*)&mid_hi[wave][0][l15][0] + off);
        short8 ah1 = *(const short8*)((char*)&mid_hi[wave][1][l15][0] + off);
        short8 al0 = *(const short8*)((char*)&mid_lo[wave][0][l15][0] + off);
        short8 al1 = *(const short8*)((char*)&mid_lo[wave][1][l15][0] + off);
#pragma unroll
        for (int nt = 0; nt < 8; ++nt) {
            short8 whi = wp2[(ks * 8 + nt) * 64 + l];
            short8 wlo = wp2l[(ks * 8 + nt) * 64 + l];
            acc2[0][nt] = __builtin_amdgcn_mfma_f32_16x16x32_bf16(ah0, whi, acc2[0][nt], 0, 0, 0);
            acc2[0][nt] = __builtin_amdgcn_mfma_f32_16x16x32_bf16(al0, whi, acc2[0][nt], 0, 0, 0);
            acc2[0][nt] = __builtin_amdgcn_mfma_f32_16x16x32_bf16(ah0, wlo, acc2[0][nt], 0, 0, 0);
            acc2[1][nt] = __builtin_amdgcn_mfma_f32_16x16x32_bf16(ah1, whi, acc2[1][nt], 0, 0, 0);
            acc2[1][nt] = __builtin_amdgcn_mfma_f32_16x16x32_bf16(al1, whi, acc2[1][nt], 0, 0, 0);
            acc2[1][nt] = __builtin_amdgcn_mfma_f32_16x16x32_bf16(ah1, wlo, acc2[1][nt], 0, 0, 0);
        }
    }

    float b2v[8];
#pragma unroll
    for (int nt = 0; nt < 8; ++nt) b2v[nt] = b2[nt * 16 + l15];

    float s[8], q[8];
#pragma unroll
    for (int nt = 0; nt < 8; ++nt) { s[nt] = 0.0f; q[nt] = 0.0f; }

#pragma unroll
    for (int m = 0; m < 2; ++m) {
#pragma unroll
        for (int rr = 0; rr < 4; ++rr) {
            int rg = row_base + m * 16 + l4 * 4 + rr;
            bool ok = rg < N_NODES;
#pragma unroll
            for (int nt = 0; nt < 8; ++nt) {
                float v = fmaxf(acc2[m][nt][rr] + b2v[nt], 0.0f);   // outer ReLU
                if (ok) {
                    raw_h[(size_t)rg * 128 + nt * 16 + l15] = f2h(v);
                    s[nt] += v;
                    q[nt] += v * v;
                }
            }
        }
    }
#pragma unroll
    for (int nt = 0; nt < 8; ++nt) {
        s[nt] += __shfl_xor(s[nt], 16); s[nt] += __shfl_xor(s[nt], 32);
        q[nt] += __shfl_xor(q[nt], 16); q[nt] += __shfl_xor(q[nt], 32);
    }
    if (l4 == 0) {
#pragma unroll
        for (int nt = 0; nt < 8; ++nt) {
            red_s[wave][nt * 16 + l15] = s[nt];
            red_q[wave][nt * 16 + l15] = q[nt];
        }
    }
    __syncthreads();
    if (t < 128) {
        part_s[blockIdx.x * 128 + t] = red_s[0][t] + red_s[1][t];
        part_q[blockIdx.x * 128 + t] = red_q[0][t] + red_q[1][t];
    }
}

// 256 blocks: block b reduces channel (b&127) of (b>>7 ? part_q : part_s)
__global__ __launch_bounds__(256) void bn_reduce(
        const float* __restrict__ part_s, const float* __restrict__ part_q,
        float* __restrict__ bn_sum, float* __restrict__ bn_sq, int nparts) {
    __shared__ float red[256];
    int c = blockIdx.x & 127;
    const float* src = (blockIdx.x >> 7) ? part_q : part_s;
    float* dst = (blockIdx.x >> 7) ? bn_sq : bn_sum;
    float a = 0.0f;
    for (int p = threadIdx.x; p < nparts; p += 256) a += src[p * 128 + c];
    red[threadIdx.x] = a;
    __syncthreads();
    for (int s = 128; s > 0; s >>= 1) {
        if (threadIdx.x < s) red[threadIdx.x] += red[threadIdx.x + s];
        __syncthreads();
    }
    if (threadIdx.x == 0) dst[c] = red[0];
}

// final layer: read fp16 raw, normalize, write xs[4] fp32 + final-h fp32
__global__ void bn_apply_last(const uint2* __restrict__ hraw,
                              float4* __restrict__ xs, float4* __restrict__ fin,
                              const float* __restrict__ bn_sum, const float* __restrict__ bn_sq,
                              const float* __restrict__ gamma, const float* __restrict__ beta) {
    int i4 = blockIdx.x * 256 + threadIdx.x;
    if (i4 >= N_NODES * DIM / 4) return;
    uint2 u = hraw[i4];
    float vv[4] = { h2f(u.x & 0xFFFFu), h2f(u.x >> 16),
                    h2f(u.y & 0xFFFFu), h2f(u.y >> 16) };
    int c0 = (i4 & 31) * 4;
    const float invN = 1.0f / (float)N_NODES;
    float4 o;
    float* op = (float*)&o;
#pragma unroll
    for (int j = 0; j < 4; ++j) {
        int c = c0 + j;
        float mean = bn_sum[c] * invN;
        float var = fmaxf(bn_sq[c] * invN - mean * mean, 0.0f);
        float inv = rsqrtf(var + BN_EPS);
        op[j] = (vv[j] - mean) * inv * gamma[c] + beta[c];
    }
    xs[i4] = o;
    fin[i4] = o;
}

// ---------------- launch ----------------

extern "C" void kernel_launch(void* const* d_in, const int* in_sizes, int n_in,
                              void* d_out, int out_size, void* d_ws, size_t ws_size,
                              hipStream_t stream) {
    const float* x     = (const float*)d_in[0];
    const int*   eidx  = (const int*)d_in[1];
    const float* W1    = (const float*)d_in[3];
    const float* b1    = (const float*)d_in[4];
    const float* W2    = (const float*)d_in[5];
    const float* b2    = (const float*)d_in[6];
    const float* gamma = (const float*)d_in[7];
    const float* beta  = (const float*)d_in[8];

    int n_edges = in_sizes[1] / 2;
    const int* src = eidx;
    const int* dst = eidx + n_edges;

    const int NBLK = (N_NODES + 63) / 64;    // 782 mlp blocks

    int* counts    = (int*)d_ws;                       // 50000
    int* offsets   = counts + N_NODES;                 // 50001
    int* cursor    = offsets + N_NODES + 1;            // 50000
    int* blocksums = cursor + N_NODES;                 // 256
    int* csr_src   = blocksums + 256;                  // n_edges
    float* part_s  = (float*)(csr_src + n_edges);      // NBLK*128
    float* part_q  = part_s + NBLK * 128;              // NBLK*128
    float* bn_sum  = part_q + NBLK * 128;              // 128
    float* bn_sq   = bn_sum + DIM;                     // 128
    size_t wp_off = (((size_t)(bn_sq + DIM) - (size_t)d_ws) + 15) & ~(size_t)15;
    unsigned short* wp = (unsigned short*)((char*)d_ws + wp_off);   // 5*2*32768 bf16 (hi+lo)
    // shared fp16 node-feature table (x for layer 0, then raw(i) after mlp(i))
    size_t tb_off = (wp_off + (size_t)N_LAYERS * 2 * 32768 * 2 + 15) & ~(size_t)15;
    unsigned short* tbl = (unsigned short*)((char*)d_ws + tb_off);  // [N][128] halves = 12.8 MB

    float* out = (float*)d_out;
    // slot 0 doubles as the fp16 aggregated-sum table until bn_apply_last
    uint4* hsum4 = (uint4*)d_out;                                   // [N][16] uint4 = 12.8 MB

    // CSR build
    hipMemsetAsync(counts, 0, N_NODES * sizeof(int), stream);
    hist_kernel<<<(n_edges + 255) / 256, 256, 0, stream>>>(dst, n_edges, counts);
    int nb = (N_NODES + 255) / 256;
    scan_local<<<nb, 256, 0, stream>>>(counts, N_NODES, offsets, blocksums);
    scan_block<<<1, 256, 0, stream>>>(blocksums, nb);
    scan_add<<<nb, 256, 0, stream>>>(offsets, cursor, blocksums, N_NODES, n_edges);
    scatter_kernel<<<(n_edges + 255) / 256, 256, 0, stream>>>(src, dst, n_edges, cursor, csr_src);

    wpack_prep<<<(N_LAYERS * 2 * 16384 + 255) / 256, 256, 0, stream>>>(W1, W2, wp);
    convert_x_f16<<<(N_NODES * DIM / 4 + 255) / 256, 256, 0, stream>>>(
        (const float4*)x, (uint2*)tbl, N_NODES * DIM / 4);

    const int AGG_BLKS = (N_NODES + 3) / 4;
    for (int i = 0; i < N_LAYERS; ++i) {
        // agg(i): gather tbl (= x for i==0, raw(i-1) otherwise); for i>0 apply
        // layer-(i-1) BN affine to the sum and emit xs[i-1] from the self term.
        agg_f16<<<AGG_BLKS, 256, 0, stream>>>(
            (const uint4*)tbl, csr_src, offsets,
            (i > 0) ? bn_sum : (const float*)nullptr, bn_sq,
            (i > 0) ? gamma + (size_t)(i - 1) * DIM : (const float*)nullptr,
            (i > 0) ? beta + (size_t)(i - 1) * DIM : (const float*)nullptr,
            (i > 0) ? out + (size_t)i * N_NODES * DIM : (float*)nullptr,
            hsum4);
        // mlp(i): GEMMs on fp16 sums (in-register hi/lo split), overwrite tbl
        // with raw(i) fp16, emit BN partials
        mlp_mfma<<<NBLK, 128, 0, stream>>>(
            hsum4,
            (const short8*)(wp + (size_t)(i * 2) * 32768), b1 + (size_t)i * DIM,
            (const short8*)(wp + (size_t)(i * 2 + 1) * 32768), b2 + (size_t)i * DIM,
            tbl, part_s, part_q);
        bn_reduce<<<256, 256, 0, stream>>>(part_s, part_q, bn_sum, bn_sq, NBLK);
    }
    bn_apply_last<<<(N_NODES * DIM / 4 + 255) / 256, 256, 0, stream>>>(
        (const uint2*)tbl,
        (float4*)(out + (size_t)N_LAYERS * N_NODES * DIM), (float4*)out,
        bn_sum, bn_sq, gamma + (size_t)(N_LAYERS - 1) * DIM,
        beta + (size_t)(N_LAYERS - 1) * DIM);
}

// Round 15
// 510.384 us; speedup vs baseline: 1.2194x; 1.0203x over previous
//
#include <hip/hip_runtime.h>
#include <hip/hip_fp16.h>

#define N_NODES 50000
#define DIM 128
#define N_LAYERS 5
#define BN_EPS 1e-5f

typedef __attribute__((ext_vector_type(8))) short short8;
typedef __attribute__((ext_vector_type(4))) float f32x4;

__device__ __forceinline__ float bf2f(unsigned int u16) {
    union { unsigned int i; float f; } c; c.i = u16 << 16; return c.f;
}
__device__ __forceinline__ unsigned short f2bf(float f) {
    union { float f; unsigned int i; } c; c.f = f;
    unsigned int v = c.i + 0x7FFFu + ((c.i >> 16) & 1u);   // RNE
    return (unsigned short)(v >> 16);
}
__device__ __forceinline__ unsigned short f2h(float f) {
    __half h = __float2half(f);
    return *reinterpret_cast<unsigned short*>(&h);
}
__device__ __forceinline__ float h2f(unsigned short u) {
    __half h = *reinterpret_cast<__half*>(&u);
    return __half2float(h);
}

// ---------------- CSR build ----------------

__global__ void hist_kernel(const int* __restrict__ dst, int n_edges, int* __restrict__ counts) {
    int e = blockIdx.x * 256 + threadIdx.x;
    if (e < n_edges) atomicAdd(&counts[dst[e]], 1);
}

__global__ void scan_local(const int* __restrict__ counts, int n,
                           int* __restrict__ offsets, int* __restrict__ blocksums) {
    __shared__ int temp[256];
    int t = threadIdx.x;
    int i = blockIdx.x * 256 + t;
    int v = (i < n) ? counts[i] : 0;
    temp[t] = v;
    __syncthreads();
    for (int off = 1; off < 256; off <<= 1) {
        int add = (t >= off) ? temp[t - off] : 0;
        __syncthreads();
        temp[t] += add;
        __syncthreads();
    }
    if (i < n) offsets[i] = temp[t] - v;
    if (t == 255) blocksums[blockIdx.x] = temp[255];
}

__global__ void scan_block(int* __restrict__ blocksums, int nb) {
    __shared__ int temp[256];
    int t = threadIdx.x;
    int v = (t < nb) ? blocksums[t] : 0;
    temp[t] = v;
    __syncthreads();
    for (int off = 1; off < 256; off <<= 1) {
        int add = (t >= off) ? temp[t - off] : 0;
        __syncthreads();
        temp[t] += add;
        __syncthreads();
    }
    if (t < nb) blocksums[t] = temp[t] - v;
}

__global__ void scan_add(int* __restrict__ offsets, int* __restrict__ cursor,
                         const int* __restrict__ blocksums, int n, int n_edges) {
    int i = blockIdx.x * 256 + threadIdx.x;
    if (i < n) {
        int val = offsets[i] + blocksums[blockIdx.x];
        offsets[i] = val;
        cursor[i] = val;
    }
    if (i == 0) offsets[n] = n_edges;
}

__global__ void scatter_kernel(const int* __restrict__ src, const int* __restrict__ dst,
                               int n_edges, int* __restrict__ cursor, int* __restrict__ csr_src) {
    int e = blockIdx.x * 256 + threadIdx.x;
    if (e < n_edges) {
        int p = atomicAdd(&cursor[dst[e]], 1);
        csr_src[p] = src[e];
    }
}

// ---------------- prep ----------------

// pack W1/W2 (all layers) into MFMA B-fragment order, single fp16 plane.
__global__ void wpack_prep(const float* __restrict__ W1, const float* __restrict__ W2,
                           unsigned short* __restrict__ wp) {
    int idx = blockIdx.x * 256 + threadIdx.x;
    if (idx >= N_LAYERS * 2 * 16384) return;
    int j    = idx & 7;
    int lane = (idx >> 3) & 63;
    int nt   = (idx >> 9) & 7;
    int ks   = (idx >> 12) & 3;
    int mat  = (idx >> 14) & 1;
    int lay  = idx >> 15;
    int l15 = lane & 15, l4 = lane >> 4;
    int col = nt * 16 + l15;
    int kp = ks * 32 + l4 * 8 + j;
    int k = mat ? ((kp & 7) * 16 + (kp >> 3)) : kp;
    const float* W = mat ? W2 : W1;
    float w = W[((size_t)lay * 128 + k) * 128 + col];
    size_t base = (size_t)(lay * 2 + mat) * 16384;
    size_t inner = (size_t)((ks * 8 + nt) * 64 + lane) * 8 + j;
    wp[base + inner] = f2h(w);
}

// x (fp32) -> fp16 table
__global__ void convert_x_f16(const float4* __restrict__ x, uint2* __restrict__ xh, int n4) {
    int i = blockIdx.x * 256 + threadIdx.x;
    if (i >= n4) return;
    float4 v = x[i];
    uint2 o;
    o.x = (unsigned int)f2h(v.x) | ((unsigned int)f2h(v.y) << 16);
    o.y = (unsigned int)f2h(v.z) | ((unsigned int)f2h(v.w) << 16);
    xh[i] = o;
}

// ---------------- fused aggregation + BN-affine fold ----------------
// Gathers fp16 RAW features (pre-BN), applies the previous layer's BN affine
// to the SUM (BN commutes: sum(A*h+B) = A*sum(h) + B*cnt), writes the fp16
// aggregated-sum table for the MLP, and emits xs[i-1] from the self term.
// Quarter-wave gathers: 16 lanes x uint4 (8 halves) per 256B row, 4 edges per
// instruction, depth-8 = 32 edges in flight per wave.
__global__ void agg_f16(const uint4* __restrict__ tbl4, const int* __restrict__ csr_src,
                        const int* __restrict__ offsets,
                        const float* __restrict__ bn_sum, const float* __restrict__ bn_sq,
                        const float* __restrict__ gamma, const float* __restrict__ beta,
                        float* __restrict__ xs_out,
                        uint4* __restrict__ hsum4) {
    int wave = threadIdx.x >> 6;
    int l = threadIdx.x & 63;
    int node = blockIdx.x * 4 + wave;
    if (node >= N_NODES) return;
    int g = l >> 4;          // edge slot 0..3
    int d = l & 15;          // uint4 chunk: channels d*8 .. d*8+7
    int beg = offsets[node], end = offsets[node + 1];

    float self[8];
    float a[8];
#pragma unroll
    for (int j = 0; j < 8; ++j) { a[j] = 0.0f; self[j] = 0.0f; }
    if (g == 0) {
        uint4 u = tbl4[(size_t)node * 16 + d];   // self term
        self[0] = h2f(u.x & 0xFFFFu); self[1] = h2f(u.x >> 16);
        self[2] = h2f(u.y & 0xFFFFu); self[3] = h2f(u.y >> 16);
        self[4] = h2f(u.z & 0xFFFFu); self[5] = h2f(u.z >> 16);
        self[6] = h2f(u.w & 0xFFFFu); self[7] = h2f(u.w >> 16);
#pragma unroll
        for (int j = 0; j < 8; ++j) a[j] = self[j];
    }

    for (int e = beg; e < end; e += 32) {
        int s[8];
#pragma unroll
        for (int i = 0; i < 8; ++i) s[i] = csr_src[min(e + 4 * i + g, end - 1)];
        uint4 v[8];
#pragma unroll
        for (int i = 0; i < 8; ++i) v[i] = tbl4[(size_t)s[i] * 16 + d];
#pragma unroll
        for (int i = 0; i < 8; ++i) {
            float w = (e + 4 * i + g < end) ? 1.0f : 0.0f;   // mask tail
            a[0] = fmaf(h2f(v[i].x & 0xFFFFu), w, a[0]);
            a[1] = fmaf(h2f(v[i].x >> 16),     w, a[1]);
            a[2] = fmaf(h2f(v[i].y & 0xFFFFu), w, a[2]);
            a[3] = fmaf(h2f(v[i].y >> 16),     w, a[3]);
            a[4] = fmaf(h2f(v[i].z & 0xFFFFu), w, a[4]);
            a[5] = fmaf(h2f(v[i].z >> 16),     w, a[5]);
            a[6] = fmaf(h2f(v[i].w & 0xFFFFu), w, a[6]);
            a[7] = fmaf(h2f(v[i].w >> 16),     w, a[7]);
        }
    }

    // reduce across the 4 edge slots (lanes l, l^16, l^32, l^48 share d)
#pragma unroll
    for (int j = 0; j < 8; ++j) {
        a[j] += __shfl_xor(a[j], 16);
        a[j] += __shfl_xor(a[j], 32);
    }

    if (g != 0) return;

    // BN-affine fold (prev layer): z = A*sum + B*cnt ; xs = A*self + B
    if (bn_sum) {
        const float invN = 1.0f / (float)N_NODES;
        float cnt = (float)(end - beg + 1);
#pragma unroll
        for (int j = 0; j < 8; ++j) {
            int c = d * 8 + j;
            float mean = bn_sum[c] * invN;
            float var = fmaxf(bn_sq[c] * invN - mean * mean, 0.0f);
            float inv = rsqrtf(var + BN_EPS);
            float A = gamma[c] * inv;
            float B = beta[c] - mean * A;
            a[j] = A * a[j] + B * cnt;
            self[j] = A * self[j] + B;
        }
        if (xs_out) {
            float4 o0 = make_float4(self[0], self[1], self[2], self[3]);
            float4 o1 = make_float4(self[4], self[5], self[6], self[7]);
            ((float4*)xs_out)[(size_t)node * 32 + d * 2]     = o0;
            ((float4*)xs_out)[(size_t)node * 32 + d * 2 + 1] = o1;
        }
    }

    uint4 o;
    o.x = (unsigned int)f2h(a[0]) | ((unsigned int)f2h(a[1]) << 16);
    o.y = (unsigned int)f2h(a[2]) | ((unsigned int)f2h(a[3]) << 16);
    o.z = (unsigned int)f2h(a[4]) | ((unsigned int)f2h(a[5]) << 16);
    o.w = (unsigned int)f2h(a[6]) | ((unsigned int)f2h(a[7]) << 16);
    hsum4[(size_t)node * 16 + d] = o;
}

// fused MFMA MLP (native fp16 MFMA): ReLU(h@W1+b1)@W2+b2 -> ReLU
// -> raw fp16 + per-block BN partials. A-fragments are the fp16 sums read
// directly from hsum; W packed fp16; mid stored fp16 in LDS.
__global__ __launch_bounds__(128) void mlp_mfma(
        const unsigned short* __restrict__ hsum,
        const short8* __restrict__ wp1, const float* __restrict__ b1,
        const short8* __restrict__ wp2, const float* __restrict__ b2,
        unsigned short* __restrict__ raw_h,
        float* __restrict__ part_s, float* __restrict__ part_q) {
    __shared__ unsigned short mid[2][2][16][128];   // [wave][m][row][kp], XOR-swizzled
    __shared__ float red_s[2][128], red_q[2][128];
    int t = threadIdx.x, wave = t >> 6, l = t & 63;
    int l15 = l & 15, l4 = l >> 4;
    int row_base = blockIdx.x * 64 + wave * 32;

    int r0 = row_base + l15, r1 = r0 + 16;
    int cr0 = min(r0, N_NODES - 1), cr1 = min(r1, N_NODES - 1);
    const short8* a0p = (const short8*)(hsum + (size_t)cr0 * 128);
    const short8* a1p = (const short8*)(hsum + (size_t)cr1 * 128);

    f32x4 acc[2][8];
#pragma unroll
    for (int m = 0; m < 2; ++m)
#pragma unroll
        for (int nt = 0; nt < 8; ++nt) acc[m][nt] = (f32x4)0.0f;

#pragma unroll
    for (int ks = 0; ks < 4; ++ks) {
        short8 a0 = a0p[ks * 4 + l4];   // A[row=l&15][k = ks*32 + (l>>4)*8 + j], fp16
        short8 a1 = a1p[ks * 4 + l4];
#pragma unroll
        for (int nt = 0; nt < 8; ++nt) {
            short8 w = wp1[(ks * 8 + nt) * 64 + l];
            acc[0][nt] = __builtin_amdgcn_mfma_f32_16x16x32_f16(a0, w, acc[0][nt], 0, 0, 0);
            acc[1][nt] = __builtin_amdgcn_mfma_f32_16x16x32_f16(a1, w, acc[1][nt], 0, 0, 0);
        }
    }

    float b1v[8];
#pragma unroll
    for (int nt = 0; nt < 8; ++nt) b1v[nt] = b1[nt * 16 + l15];

    // bias + ReLU + fp16; pack lane's 8 cols (kp = l15*8 + nt) -> LDS
#pragma unroll
    for (int m = 0; m < 2; ++m) {
#pragma unroll
        for (int rr = 0; rr < 4; ++rr) {
            int row = l4 * 4 + rr;   // C/D: row=(l>>4)*4+reg, col=nt*16+l15
            short8 pk;
#pragma unroll
            for (int nt = 0; nt < 8; ++nt) {
                float v = fmaxf(acc[m][nt][rr] + b1v[nt], 0.0f);
                pk[nt] = (short)f2h(v);
            }
            int off = (l15 * 16) ^ ((row & 7) << 4);
            *(short8*)((char*)&mid[wave][m][row][0] + off) = pk;
        }
    }
    __syncthreads();

    f32x4 acc2[2][8];
#pragma unroll
    for (int m = 0; m < 2; ++m)
#pragma unroll
        for (int nt = 0; nt < 8; ++nt) acc2[m][nt] = (f32x4)0.0f;

#pragma unroll
    for (int ks = 0; ks < 4; ++ks) {
        int off = (ks * 64 + l4 * 16) ^ ((l15 & 7) << 4);
        short8 a0 = *(const short8*)((char*)&mid[wave][0][l15][0] + off);
        short8 a1 = *(const short8*)((char*)&mid[wave][1][l15][0] + off);
#pragma unroll
        for (int nt = 0; nt < 8; ++nt) {
            short8 w = wp2[(ks * 8 + nt) * 64 + l];
            acc2[0][nt] = __builtin_amdgcn_mfma_f32_16x16x32_f16(a0, w, acc2[0][nt], 0, 0, 0);
            acc2[1][nt] = __builtin_amdgcn_mfma_f32_16x16x32_f16(a1, w, acc2[1][nt], 0, 0, 0);
        }
    }

    float b2v[8];
#pragma unroll
    for (int nt = 0; nt < 8; ++nt) b2v[nt] = b2[nt * 16 + l15];

    float s[8], q[8];
#pragma unroll
    for (int nt = 0; nt < 8; ++nt) { s[nt] = 0.0f; q[nt] = 0.0f; }

#pragma unroll
    for (int m = 0; m < 2; ++m) {
#pragma unroll
        for (int rr = 0; rr < 4; ++rr) {
            int rg = row_base + m * 16 + l4 * 4 + rr;
            bool ok = rg < N_NODES;
#pragma unroll
            for (int nt = 0; nt < 8; ++nt) {
                float v = fmaxf(acc2[m][nt][rr] + b2v[nt], 0.0f);   // outer ReLU
                if (ok) {
                    raw_h[(size_t)rg * 128 + nt * 16 + l15] = f2h(v);
                    s[nt] += v;
                    q[nt] += v * v;
                }
            }
        }
    }
#pragma unroll
    for (int nt = 0; nt < 8; ++nt) {
        s[nt] += __shfl_xor(s[nt], 16); s[nt] += __shfl_xor(s[nt], 32);
        q[nt] += __shfl_xor(q[nt], 16); q[nt] += __shfl_xor(q[nt], 32);
    }
    if (l4 == 0) {
#pragma unroll
        for (int nt = 0; nt < 8; ++nt) {
            red_s[wave][nt * 16 + l15] = s[nt];
            red_q[wave][nt * 16 + l15] = q[nt];
        }
    }
    __syncthreads();
    if (t < 128) {
        part_s[blockIdx.x * 128 + t] = red_s[0][t] + red_s[1][t];
        part_q[blockIdx.x * 128 + t] = red_q[0][t] + red_q[1][t];
    }
}

// 256 blocks: block b reduces channel (b&127) of (b>>7 ? part_q : part_s)
__global__ __launch_bounds__(256) void bn_reduce(
        const float* __restrict__ part_s, const float* __restrict__ part_q,
        float* __restrict__ bn_sum, float* __restrict__ bn_sq, int nparts) {
    __shared__ float red[256];
    int c = blockIdx.x & 127;
    const float* src = (blockIdx.x >> 7) ? part_q : part_s;
    float* dst = (blockIdx.x >> 7) ? bn_sq : bn_sum;
    float a = 0.0f;
    for (int p = threadIdx.x; p < nparts; p += 256) a += src[p * 128 + c];
    red[threadIdx.x] = a;
    __syncthreads();
    for (int s = 128; s > 0; s >>= 1) {
        if (threadIdx.x < s) red[threadIdx.x] += red[threadIdx.x + s];
        __syncthreads();
    }
    if (threadIdx.x == 0) dst[c] = red[0];
}

// final layer: read fp16 raw, normalize, write xs[4] fp32 + final-h fp32
__global__ void bn_apply_last(const uint2* __restrict__ hraw,
                              float4* __restrict__ xs, float4* __restrict__ fin,
                              const float* __restrict__ bn_sum, const float* __restrict__ bn_sq,
                              const float* __restrict__ gamma, const float* __restrict__ beta) {
    int i4 = blockIdx.x * 256 + threadIdx.x;
    if (i4 >= N_NODES * DIM / 4) return;
    uint2 u = hraw[i4];
    float vv[4] = { h2f(u.x & 0xFFFFu), h2f(u.x >> 16),
                    h2f(u.y & 0xFFFFu), h2f(u.y >> 16) };
    int c0 = (i4 & 31) * 4;
    const float invN = 1.0f / (float)N_NODES;
    float4 o;
    float* op = (float*)&o;
#pragma unroll
    for (int j = 0; j < 4; ++j) {
        int c = c0 + j;
        float mean = bn_sum[c] * invN;
        float var = fmaxf(bn_sq[c] * invN - mean * mean, 0.0f);
        float inv = rsqrtf(var + BN_EPS);
        op[j] = (vv[j] - mean) * inv * gamma[c] + beta[c];
    }
    xs[i4] = o;
    fin[i4] = o;
}

// ---------------- launch ----------------

extern "C" void kernel_launch(void* const* d_in, const int* in_sizes, int n_in,
                              void* d_out, int out_size, void* d_ws, size_t ws_size,
                              hipStream_t stream) {
    const float* x     = (const float*)d_in[0];
    const int*   eidx  = (const int*)d_in[1];
    const float* W1    = (const float*)d_in[3];
    const float* b1    = (const float*)d_in[4];
    const float* W2    = (const float*)d_in[5];
    const float* b2    = (const float*)d_in[6];
    const float* gamma = (const float*)d_in[7];
    const float* beta  = (const float*)d_in[8];

    int n_edges = in_sizes[1] / 2;
    const int* src = eidx;
    const int* dst = eidx + n_edges;

    const int NBLK = (N_NODES + 63) / 64;    // 782 mlp blocks

    int* counts    = (int*)d_ws;                       // 50000
    int* offsets   = counts + N_NODES;                 // 50001
    int* cursor    = offsets + N_NODES + 1;            // 50000
    int* blocksums = cursor + N_NODES;                 // 256
    int* csr_src   = blocksums + 256;                  // n_edges
    float* part_s  = (float*)(csr_src + n_edges);      // NBLK*128
    float* part_q  = part_s + NBLK * 128;              // NBLK*128
    float* bn_sum  = part_q + NBLK * 128;              // 128
    float* bn_sq   = bn_sum + DIM;                     // 128
    size_t wp_off = (((size_t)(bn_sq + DIM) - (size_t)d_ws) + 15) & ~(size_t)15;
    unsigned short* wp = (unsigned short*)((char*)d_ws + wp_off);   // 5*2*16384 fp16
    // shared fp16 node-feature table (x for layer 0, then raw(i) after mlp(i))
    size_t tb_off = (wp_off + (size_t)N_LAYERS * 2 * 16384 * 2 + 15) & ~(size_t)15;
    unsigned short* tbl = (unsigned short*)((char*)d_ws + tb_off);  // [N][128] halves = 12.8 MB

    float* out = (float*)d_out;
    // slot 0 doubles as the fp16 aggregated-sum table until bn_apply_last
    uint4* hsum4 = (uint4*)d_out;                                   // [N][16] uint4 = 12.8 MB

    // CSR build
    hipMemsetAsync(counts, 0, N_NODES * sizeof(int), stream);
    hist_kernel<<<(n_edges + 255) / 256, 256, 0, stream>>>(dst, n_edges, counts);
    int nb = (N_NODES + 255) / 256;
    scan_local<<<nb, 256, 0, stream>>>(counts, N_NODES, offsets, blocksums);
    scan_block<<<1, 256, 0, stream>>>(blocksums, nb);
    scan_add<<<nb, 256, 0, stream>>>(offsets, cursor, blocksums, N_NODES, n_edges);
    scatter_kernel<<<(n_edges + 255) / 256, 256, 0, stream>>>(src, dst, n_edges, cursor, csr_src);

    wpack_prep<<<(N_LAYERS * 2 * 16384 + 255) / 256, 256, 0, stream>>>(W1, W2, wp);
    convert_x_f16<<<(N_NODES * DIM / 4 + 255) / 256, 256, 0, stream>>>(
        (const float4*)x, (uint2*)tbl, N_NODES * DIM / 4);

    const int AGG_BLKS = (N_NODES + 3) / 4;
    for (int i = 0; i < N_LAYERS; ++i) {
        // agg(i): gather tbl (= x for i==0, raw(i-1) otherwise); for i>0 apply
        // layer-(i-1) BN affine to the sum and emit xs[i-1] from the self term.
        agg_f16<<<AGG_BLKS, 256, 0, stream>>>(
            (const uint4*)tbl, csr_src, offsets,
            (i > 0) ? bn_sum : (const float*)nullptr, bn_sq,
            (i > 0) ? gamma + (size_t)(i - 1) * DIM : (const float*)nullptr,
            (i > 0) ? beta + (size_t)(i - 1) * DIM : (const float*)nullptr,
            (i > 0) ? out + (size_t)i * N_NODES * DIM : (float*)nullptr,
            hsum4);
        // mlp(i): native fp16 GEMMs, overwrite tbl with raw(i) fp16, BN partials
        mlp_mfma<<<NBLK, 128, 0, stream>>>(
            (const unsigned short*)hsum4,
            (const short8*)(wp + (size_t)(i * 2) * 16384), b1 + (size_t)i * DIM,
            (const short8*)(wp + (size_t)(i * 2 + 1) * 16384), b2 + (size_t)i * DIM,
            tbl, part_s, part_q);
        bn_reduce<<<256, 256, 0, stream>>>(part_s, part_q, bn_sum, bn_sq, NBLK);
    }
    bn_apply_last<<<(N_NODES * DIM / 4 + 255) / 256, 256, 0, stream>>>(
        (const uint2*)tbl,
        (float4*)(out + (size_t)N_LAYERS * N_NODES * DIM), (float4*)out,
        bn_sum, bn_sq, gamma + (size_t)(N_LAYERS - 1) * DIM,
        beta + (size_t)(N_LAYERS - 1) * DIM);
}